// Round 12
// baseline (1231.182 us; speedup 1.0000x reference)
//
#include <hip/hip_runtime.h>
#include <stdint.h>

#define B_    2
#define SEQ   2048
#define HID   2048
#define NK_   16
#define NV_   32
#define DK_   128
#define DV_   128
#define NQKVZ 12288
#define CONVD 8192
#define MTOT  (B_*SEQ)   // 4096
#define CCH   16         // recurrence sub-chunk length

typedef unsigned short ushort_t;
typedef __bf16 bf16x8 __attribute__((ext_vector_type(8)));
typedef float  f32x4  __attribute__((ext_vector_type(4)));
typedef unsigned short us4 __attribute__((ext_vector_type(4)));

__device__ __forceinline__ ushort_t f2bf(float f){
  union { float f; unsigned u; } v; v.f = f;
  unsigned r = v.u + 0x7FFFu + ((v.u >> 16) & 1u);
  return (ushort_t)(r >> 16);
}
__device__ __forceinline__ float bf2f(ushort_t u){
  union { unsigned u; float f; } v; v.u = ((unsigned)u) << 16; return v.f;
}
__device__ __forceinline__ float sigmoidf_(float x){ return 1.f/(1.f+__expf(-x)); }
__device__ __forceinline__ float siluf_(float x){ return x*sigmoidf_(x); }

// ---------------- cast x -> bf16 ----------------
__global__ void cast_x_kernel(const float* __restrict__ x, ushort_t* __restrict__ xb, int n4){
  int i = blockIdx.x*256 + threadIdx.x;
  if (i >= n4) return;
  float4 v = ((const float4*)x)[i];
  us4 o; o[0]=f2bf(v.x); o[1]=f2bf(v.y); o[2]=f2bf(v.z); o[3]=f2bf(v.w);
  ((us4*)xb)[i] = o;
}

// ---------------- transpose + cast W[K][N] -> Wt[N][K] bf16 ----------------
__global__ __launch_bounds__(256) void transpose_cast(const float* __restrict__ W, ushort_t* __restrict__ Wt,
                                                      int K, int N){
  __shared__ float tile[64][65];
  int n0 = blockIdx.x*64, k0 = blockIdx.y*64;
  int tx = threadIdx.x & 63, ty = threadIdx.x >> 6;
  #pragma unroll
  for (int i=0;i<16;i++){
    int kr = ty + i*4;
    tile[kr][tx] = W[(size_t)(k0+kr)*N + n0+tx];
  }
  __syncthreads();
  #pragma unroll
  for (int i=0;i<16;i++){
    int nr = ty + i*4;
    Wt[(size_t)(n0+nr)*K + k0+tx] = f2bf(tile[tx][nr]);
  }
}

// ---------------- bf16 MFMA GEMM (global_load_lds staging) ----------------
template<int OUTBF>
__global__ __launch_bounds__(256) void gemm_bf16(const ushort_t* __restrict__ A, const ushort_t* __restrict__ Bt,
                                                 void* __restrict__ Cv, int M, int N, int K){
  __shared__ ushort_t As[128][32];
  __shared__ ushort_t Bs[128][32];
  const int t = threadIdx.x;
  const int lane = t & 63, w = t >> 6;
  const int wm = w >> 1, wn = w & 1;
  const int m0 = blockIdx.y * 128, n0 = blockIdx.x * 128;
  const int srow = lane >> 2;
  const int scol = (lane & 3) * 8;
  const ushort_t* gA0 = &A [(size_t)(m0 +      w*16 + srow)*K + scol];
  const ushort_t* gA1 = &A [(size_t)(m0 + 64 + w*16 + srow)*K + scol];
  const ushort_t* gB0 = &Bt[(size_t)(n0 +      w*16 + srow)*K + scol];
  const ushort_t* gB1 = &Bt[(size_t)(n0 + 64 + w*16 + srow)*K + scol];
  ushort_t* lA0 = &As[     w*16][0];
  ushort_t* lA1 = &As[64 + w*16][0];
  ushort_t* lB0 = &Bs[     w*16][0];
  ushort_t* lB1 = &Bs[64 + w*16][0];
  f32x4 acc[4][4];
  #pragma unroll
  for (int i=0;i<4;i++)
    #pragma unroll
    for (int j=0;j<4;j++) acc[i][j] = (f32x4){0.f,0.f,0.f,0.f};
  const int lr = lane & 15, lk = (lane >> 4) * 8;
  for (int k0 = 0; k0 < K; k0 += 32){
    __builtin_amdgcn_global_load_lds((const __attribute__((address_space(1))) void*)(gA0 + k0),
                                     (__attribute__((address_space(3))) void*)lA0, 16, 0, 0);
    __builtin_amdgcn_global_load_lds((const __attribute__((address_space(1))) void*)(gA1 + k0),
                                     (__attribute__((address_space(3))) void*)lA1, 16, 0, 0);
    __builtin_amdgcn_global_load_lds((const __attribute__((address_space(1))) void*)(gB0 + k0),
                                     (__attribute__((address_space(3))) void*)lB0, 16, 0, 0);
    __builtin_amdgcn_global_load_lds((const __attribute__((address_space(1))) void*)(gB1 + k0),
                                     (__attribute__((address_space(3))) void*)lB1, 16, 0, 0);
    __syncthreads();
    bf16x8 af[4], bfv[4];
    #pragma unroll
    for (int i=0;i<4;i++) af[i]  = *(const bf16x8*)&As[wm*64 + i*16 + lr][lk];
    #pragma unroll
    for (int j=0;j<4;j++) bfv[j] = *(const bf16x8*)&Bs[wn*64 + j*16 + lr][lk];
    #pragma unroll
    for (int i=0;i<4;i++)
      #pragma unroll
      for (int j=0;j<4;j++)
        acc[i][j] = __builtin_amdgcn_mfma_f32_16x16x32_bf16(af[i], bfv[j], acc[i][j], 0, 0, 0);
    __syncthreads();
  }
  const int lg = lane >> 4;
  #pragma unroll
  for (int i=0;i<4;i++)
    #pragma unroll
    for (int j=0;j<4;j++)
      #pragma unroll
      for (int r=0;r<4;r++){
        int m = m0 + wm*64 + i*16 + lg*4 + r;
        int n = n0 + wn*64 + j*16 + lr;
        if (OUTBF) ((ushort_t*)Cv)[(size_t)m*N + n] = f2bf(acc[i][j][r]);
        else       ((float*)Cv)[(size_t)m*N + n]    = acc[i][j][r];
      }
}

// ---------------- ba = x @ W_ba (fp32, N=64) ----------------
__global__ __launch_bounds__(256) void gemm_ba(const float* __restrict__ x, const float* __restrict__ Wba,
                                               float* __restrict__ ba){
  int lane = threadIdx.x & 63;
  int wid  = threadIdx.x >> 6;
  int row  = blockIdx.x*4 + wid;
  const float* xr = x + (size_t)row*HID;
  float acc = 0.f;
  for (int k=0;k<HID;k+=4){
    float4 xv = *(const float4*)&xr[k];
    acc += xv.x * Wba[(size_t)(k+0)*64 + lane];
    acc += xv.y * Wba[(size_t)(k+1)*64 + lane];
    acc += xv.z * Wba[(size_t)(k+2)*64 + lane];
    acc += xv.w * Wba[(size_t)(k+3)*64 + lane];
  }
  ba[(size_t)row*64 + lane] = acc;
}

// ---------------- conv(k=4) + SiLU + q/k RMS-norm (bf16 in/out) ----------------
__global__ __launch_bounds__(128) void conv_norm_kernel(const ushort_t* __restrict__ qkvz, const float* __restrict__ conv_w,
                                                        ushort_t* __restrict__ qkv){
  __shared__ float red[2];
  const int blk = blockIdx.x;
  const int gi = blk & 63;
  const int bt = blk >> 6;
  const int ts = bt & (SEQ-1);
  const int dk = threadIdx.x;
  int col;
  if (gi < 16)       col = gi*768 + dk;
  else if (gi < 32)  col = (gi-16)*768 + 128 + dk;
  else { int nv = gi-32; col = (nv>>1)*768 + 256 + (nv&1)*128 + dk; }
  const int c = gi*128 + dk;
  const float4 w = *(const float4*)&conv_w[(size_t)c*4];
  float a0 = (ts>=3) ? bf2f(qkvz[(size_t)(bt-3)*NQKVZ + col]) : 0.f;
  float a1 = (ts>=2) ? bf2f(qkvz[(size_t)(bt-2)*NQKVZ + col]) : 0.f;
  float a2 = (ts>=1) ? bf2f(qkvz[(size_t)(bt-1)*NQKVZ + col]) : 0.f;
  float a3 =           bf2f(qkvz[(size_t)(bt  )*NQKVZ + col]);
  float acc = a0*w.x + a1*w.y + a2*w.z + a3*w.w;
  float y = siluf_(acc);
  float outv = y;
  if (gi < 32){
    float ss = y*y;
    #pragma unroll
    for (int o=1;o<64;o<<=1) ss += __shfl_xor(ss, o);
    if ((threadIdx.x & 63) == 0) red[threadIdx.x>>6] = ss;
    __syncthreads();
    float tot = red[0] + red[1];
    float rs = rsqrtf(tot*(1.f/128.f) + 1e-6f);
    float scale = (gi < 16) ? (1.f/128.f) : 0.08838834764831845f;
    outv = y*rs*scale;
  }
  qkv[(size_t)bt*CONVD + gi*128 + dk] = f2bf(outv);
}

// ---------------- {g, beta} as float2 (g in LOG space) ----------------
__global__ void gbeta_kernel(const float* __restrict__ ba, const float* __restrict__ A_log,
                             const float* __restrict__ dt_bias, float2* __restrict__ egb){
  int idx = blockIdx.x*256 + threadIdx.x;
  if (idx >= MTOT*NV_) return;
  int nv = idx & 31;
  int bt = idx >> 5;
  int nk = nv >> 1, r = nv & 1;
  float bg = ba[(size_t)bt*64 + nk*4 + r];
  float ag = ba[(size_t)bt*64 + nk*4 + 2 + r];
  float ad = ag + dt_bias[nv];
  float sp = fmaxf(ad, 0.f) + log1pf(__expf(-fabsf(ad)));
  float g  = -__expf(A_log[nv]) * sp;
  egb[idx] = make_float2(g, sigmoidf_(bg));
}

// ---------------- chunked gated delta-rule, CCH=16, dv-octant blocks ----------------
// grid = 512 blocks (64 heads x 8 dv-octants of 16) -> 2 blocks/CU; 512 threads = 8 waves.
// Every matrix is one 16x16 tile: KS0->w0, A->w1, QS0->w4, W->w5; state S^T[16dv][128dk]
// split 8 dk-tiles, one per wave. All small-matrix rows 40-elem (20-dword) stride: conflict-free.
__global__ __launch_bounds__(512, 4) void recurrence_v3(const ushort_t* __restrict__ qkv,
                                                        const float2* __restrict__ egb,
                                                        float* __restrict__ outc){
  const int bid = blockIdx.x;
  const int bi  = ((bid & 7) << 6) | (bid >> 3);    // XCD-chunked, bijective (512 % 8 == 0)
  const int b   = bi >> 8;
  const int nv  = (bi >> 3) & 31;
  const int oc  = bi & 7;
  const int nk  = nv >> 1;
  const int t = threadIdx.x, lane = t & 63, w = t >> 6;
  const int lr = lane & 15, hk = lane >> 4;

  __shared__ ushort_t Kl [16*136];   // K chunk [t][dk], 136-pad (272B rows -> 2-way max)
  __shared__ ushort_t S0h[16*136];   // S^T hi [dv][dk]
  __shared__ ushort_t S0l[16*136];   // S^T lo
  __shared__ ushort_t KT [128*40];   // K'^T [dk][t], cols 16..39 zero (K=32 pad)
  __shared__ ushort_t DT [16*40];    // Delta^T [dv][t], k-pad
  __shared__ ushort_t Wl [16*40];    // W [i][j], k-pad
  __shared__ float    Al [16*20];    // A f32
  __shared__ float    Ul [16*20];    // u^T [dv][t] f32
  __shared__ float    clB[2][16], blB[2][16], eclB[2][16], kslB[2][16], e15B[2];

  for (int i=t;i<128*40;i+=512) KT[i]=0;
  for (int i=t;i<16*40;i+=512){ DT[i]=0; Wl[i]=0; }
  for (int i=t;i<16*136;i+=512){ S0h[i]=0; S0l[i]=0; }

  f32x4 Sr = {0.f,0.f,0.f,0.f};
  const size_t bt0 = (size_t)b*SEQ;
  const int srow = t >> 4, scol = (t & 15)*8;   // K staging (t<256)

  // -------- prologue: chunk 0 --------
  uint4 kst = make_uint4(0,0,0,0);
  if (t < 256) kst = *(const uint4*)(qkv + (bt0+srow)*CONVD + 2048 + nk*128 + scol);
  bf16x8 qf[4];
  if (w==4 || w==5){
    const ushort_t* qrow = qkv + (bt0+lr)*CONVD + nk*128 + hk*8;
    #pragma unroll
    for (int ks=0;ks<4;ks++) qf[ks] = *(const bf16x8*)(qrow + ks*32);
  }
  ushort_t vreg[4];
  if (w==0){
    #pragma unroll
    for (int r=0;r<4;r++)
      vreg[r] = qkv[(bt0 + hk*4 + r)*CONVD + 4096 + nv*128 + oc*16 + lr];
  }
  float2 eb = make_float2(0.f,0.f);
  if (w==2 && lane<16) eb = egb[(bt0+lane)*NV_ + nv];
  if (t < 256) *(uint4*)&Kl[srow*136 + scol] = kst;
  if (w==2 && lane<16){
    float c = eb.x;
    #pragma unroll
    for (int o=1;o<16;o<<=1){ float tv = __shfl_up(c, o, 16); if (lane >= o) c += tv; }
    clB[0][lane] = c; blB[0][lane] = eb.y; eclB[0][lane] = __expf(c);
    float c15 = __shfl(c, 15, 16);
    kslB[0][lane] = __expf(c15 - c);
    if (lane==0) e15B[0] = __expf(c15);
  }
  __syncthreads();

  int pb = 0;
  for (int base = 0; base < SEQ; base += CCH){
    const int nbase = (base + CCH < SEQ) ? base + CCH : base;

    // ============ phase 1: products + A/W/u + KT ============
    bf16x8 kf[4];
    if (w <= 1 || w == 5){
      #pragma unroll
      for (int ks=0;ks<4;ks++) kf[ks] = *(const bf16x8*)&Kl[lr*136 + hk*8 + ks*32];
    }
    f32x4 ph = (f32x4){0.f,0.f,0.f,0.f}, pl = ph;
    if (w==0 || w==4){ // KS0 / QS0, hi+lo  -> C[t][dv]
      #pragma unroll
      for (int ks=0;ks<4;ks++){
        bf16x8 xf = (w==0) ? kf[ks] : qf[ks];
        bf16x8 yh = *(const bf16x8*)&S0h[lr*136 + hk*8 + ks*32];
        bf16x8 yl = *(const bf16x8*)&S0l[lr*136 + hk*8 + ks*32];
        ph = __builtin_amdgcn_mfma_f32_16x16x32_bf16(xf, yh, ph, 0,0,0);
        pl = __builtin_amdgcn_mfma_f32_16x16x32_bf16(xf, yl, pl, 0,0,0);
      }
    }
    if (w == 1){ // A = K K^T (strict lower, scaled)
      f32x4 a = (f32x4){0.f,0.f,0.f,0.f};
      #pragma unroll
      for (int ks=0;ks<4;ks++) a = __builtin_amdgcn_mfma_f32_16x16x32_bf16(kf[ks], kf[ks], a, 0,0,0);
      #pragma unroll
      for (int r=0;r<4;r++){
        int i = hk*4 + r, j = lr;
        Al[i*20 + j] = (j < i) ? blB[pb][i]*__expf(clB[pb][i]-clB[pb][j])*a[r] : 0.f;
      }
    }
    if (w == 5){ // W = Q K^T (lower incl diag, decay-scaled)
      f32x4 a = (f32x4){0.f,0.f,0.f,0.f};
      #pragma unroll
      for (int ks=0;ks<4;ks++) a = __builtin_amdgcn_mfma_f32_16x16x32_bf16(qf[ks], kf[ks], a, 0,0,0);
      #pragma unroll
      for (int r=0;r<4;r++){
        int i = hk*4 + r, j = lr;
        float val = (j <= i) ? __expf(clB[pb][i]-clB[pb][j])*a[r] : 0.f;
        Wl[i*40 + j] = f2bf(val);
      }
    }
    if (w == 0){ // u^T[dv][t] = beta_t (v - e^{c_t} KS0)
      #pragma unroll
      for (int r=0;r<4;r++){
        int tt_ = hk*4 + r;
        Ul[lr*20 + tt_] = blB[pb][tt_]*(bf2f(vreg[r]) - eclB[pb][tt_]*(ph[r] + pl[r]));
      }
    }
    { // KT build: thread dk = t>>2, cols (t&3)*4..+4
      const int dk = t >> 2, tq = t & 3;
      #pragma unroll
      for (int p=0;p<2;p++){
        int j0 = tq*4 + 2*p, j1 = j0+1;
        float v0 = kslB[pb][j0]*bf2f(Kl[j0*136 + dk]);
        float v1 = kslB[pb][j1]*bf2f(Kl[j1*136 + dk]);
        *(unsigned*)&KT[dk*40 + j0] = (unsigned)f2bf(v0) | ((unsigned)f2bf(v1) << 16);
      }
    }
    __syncthreads();   // B3: Al/Wl/Ul/KT ready

    // ============ phase 2: w0 substitution || others prefetch ============
    if (t < 256) kst = *(const uint4*)(qkv + (bt0+nbase+srow)*CONVD + 2048 + nk*128 + scol);
    if (w==4 || w==5){
      const ushort_t* qrow = qkv + (bt0 + nbase + lr)*CONVD + nk*128 + hk*8;
      #pragma unroll
      for (int ks=0;ks<4;ks++) qf[ks] = *(const bf16x8*)(qrow + ks*32);
    }
    ushort_t vnext[4];
    if (w==0){
      #pragma unroll
      for (int r=0;r<4;r++)
        vnext[r] = qkv[(bt0 + nbase + hk*4 + r)*CONVD + 4096 + nv*128 + oc*16 + lr];
    }
    float2 ebn = make_float2(0.f,0.f);
    if (w==2 && lane<16) ebn = egb[(bt0+nbase+lane)*NV_ + nv];
    bf16x8 yf = *(const bf16x8*)&KT[(w*16+lr)*40 + hk*8];   // own dk-tile of K'^T
    bf16x8 wfr = {};
    if (w == 4) wfr = *(const bf16x8*)&Wl[lr*40 + hk*8];

    if (w == 0 && lane < 16){ // forward substitution (I+A)d = u, column = lane(dv)
      float d[16];
      #pragma unroll
      for (int q=0;q<4;q++){
        float4 dd = *(const float4*)&Ul[lane*20 + q*4];
        d[4*q]=dd.x; d[4*q+1]=dd.y; d[4*q+2]=dd.z; d[4*q+3]=dd.w;
      }
      #pragma unroll
      for (int rb=0;rb<4;rb++){
        float p0=0.f,p1=0.f,p2=0.f,p3=0.f;
        #pragma unroll
        for (int jb=0;jb<rb;jb++){
          float4 A0 = *(const float4*)&Al[(rb*4+0)*20 + jb*4];
          float4 A1 = *(const float4*)&Al[(rb*4+1)*20 + jb*4];
          float4 A2 = *(const float4*)&Al[(rb*4+2)*20 + jb*4];
          float4 A3 = *(const float4*)&Al[(rb*4+3)*20 + jb*4];
          p0 += (A0.x*d[jb*4]+A0.y*d[jb*4+1]) + (A0.z*d[jb*4+2]+A0.w*d[jb*4+3]);
          p1 += (A1.x*d[jb*4]+A1.y*d[jb*4+1]) + (A1.z*d[jb*4+2]+A1.w*d[jb*4+3]);
          p2 += (A2.x*d[jb*4]+A2.y*d[jb*4+1]) + (A2.z*d[jb*4+2]+A2.w*d[jb*4+3]);
          p3 += (A3.x*d[jb*4]+A3.y*d[jb*4+1]) + (A3.z*d[jb*4+2]+A3.w*d[jb*4+3]);
        }
        const int r0 = rb*4;
        d[r0+0] -= p0;
        d[r0+1] -= p1 + Al[(r0+1)*20+r0]*d[r0];
        d[r0+2] -= p2 + Al[(r0+2)*20+r0]*d[r0] + Al[(r0+2)*20+r0+1]*d[r0+1];
        d[r0+3] -= p3 + Al[(r0+3)*20+r0]*d[r0] + Al[(r0+3)*20+r0+1]*d[r0+1] + Al[(r0+3)*20+r0+2]*d[r0+2];
      }
      unsigned dd[8];
      #pragma unroll
      for (int p=0;p<8;p++) dd[p] = (unsigned)f2bf(d[2*p]) | ((unsigned)f2bf(d[2*p+1]) << 16);
      *(uint4*)&DT[lane*40 + 0] = make_uint4(dd[0],dd[1],dd[2],dd[3]);
      *(uint4*)&DT[lane*40 + 8] = make_uint4(dd[4],dd[5],dd[6],dd[7]);
    }
    __syncthreads();   // B4: Delta ready

    // ============ phase 3: O + state update + writebacks + next staging ============
    bf16x8 dfr = *(const bf16x8*)&DT[lr*40 + hk*8];   // Delta^T rows dv
    if (w == 4){ // O = W@Delta + e^{c}(QS0)
      f32x4 oo = __builtin_amdgcn_mfma_f32_16x16x32_bf16(wfr, dfr, (f32x4){0.f,0.f,0.f,0.f}, 0,0,0);
      #pragma unroll
      for (int r=0;r<4;r++){
        int tt_ = hk*4 + r;
        outc[((bt0+base+tt_)*NV_ + nv)*(size_t)DV_ + oc*16 + lr] = oo[r] + eclB[pb][tt_]*(ph[r] + pl[r]);
      }
    }
    { // state: S^T = e^{c15} S^T + Delta^T K'  (wave owns dk-tile w)
      const float g15 = e15B[pb];
      f32x4 s = Sr; s[0]*=g15; s[1]*=g15; s[2]*=g15; s[3]*=g15;
      Sr = __builtin_amdgcn_mfma_f32_16x16x32_bf16(dfr, yf, s, 0,0,0);
      #pragma unroll
      for (int r=0;r<4;r++){
        int dv = hk*4 + r;
        int dk = w*16 + lr;
        float sv = Sr[r];
        ushort_t h = f2bf(sv);
        S0h[dv*136 + dk] = h;
        S0l[dv*136 + dk] = f2bf(sv - bf2f(h));
      }
    }
    if (t < 256) *(uint4*)&Kl[srow*136 + scol] = kst;   // stage next chunk's K
    if (w==0){ vreg[0]=vnext[0]; vreg[1]=vnext[1]; vreg[2]=vnext[2]; vreg[3]=vnext[3]; }
    if (w==2 && lane<16){   // next chunk's prefix
      float c = ebn.x;
      #pragma unroll
      for (int o=1;o<16;o<<=1){ float tv = __shfl_up(c, o, 16); if (lane >= o) c += tv; }
      clB[pb^1][lane] = c; blB[pb^1][lane] = ebn.y; eclB[pb^1][lane] = __expf(c);
      float c15 = __shfl(c, 15, 16);
      kslB[pb^1][lane] = __expf(c15 - c);
      if (lane==0) e15B[pb^1] = __expf(c15);
    }
    __syncthreads();   // B5: Kl/S0/prefix ready
    pb ^= 1;
  }
}

// ---------------- gated RMSNorm -> bf16 ----------------
__global__ __launch_bounds__(128) void gatenorm_kernel(const float* __restrict__ outc, const ushort_t* __restrict__ qkvz,
                                                       const float* __restrict__ norm_w, ushort_t* __restrict__ gated){
  __shared__ float red[2];
  const int blk = blockIdx.x;
  const int nv = blk & 31;
  const size_t bt = (size_t)(blk >> 5);
  const int dv = threadIdx.x;
  float xv = outc[(bt*NV_ + nv)*(size_t)DV_ + dv];
  float ss = xv*xv;
  #pragma unroll
  for (int o=1;o<64;o<<=1) ss += __shfl_xor(ss, o);
  if ((threadIdx.x & 63)==0) red[threadIdx.x>>6] = ss;
  __syncthreads();
  float tot = red[0]+red[1];
  float xn = xv * rsqrtf(tot*(1.f/128.f) + 1e-6f) * norm_w[dv];
  int nk = nv>>1, r = nv&1;
  float z = bf2f(qkvz[bt*NQKVZ + nk*768 + 512 + r*128 + dv]);
  gated[bt*(size_t)4096 + nv*128 + dv] = f2bf(siluf_(z)*xn);
}

extern "C" void kernel_launch(void* const* d_in, const int* in_sizes, int n_in,
                              void* d_out, int out_size, void* d_ws, size_t ws_size,
                              hipStream_t stream){
  (void)in_sizes; (void)n_in; (void)out_size; (void)ws_size;
  const float* x      = (const float*)d_in[0];
  const float* W_qkvz = (const float*)d_in[1];
  const float* W_ba   = (const float*)d_in[2];
  const float* conv_w = (const float*)d_in[3];
  const float* dt_bias= (const float*)d_in[4];
  const float* A_log  = (const float*)d_in[5];
  const float* norm_w = (const float*)d_in[6];
  const float* W_out  = (const float*)d_in[7];
  float* outp = (float*)d_out;

  char* w = (char*)d_ws;
  const size_t R0 = 0;
  const size_t R1 = 100663296;
  const size_t R2 = R1 + 67108864;
  const size_t R3 = R2 + 67108864;
  ushort_t* qkvz_bf = (ushort_t*)(w + R0);
  ushort_t* xb      = (ushort_t*)(w + R1);
  ushort_t* wqt     = (ushort_t*)(w + R1 + 16777216);
  ushort_t* qkv_bf  = (ushort_t*)(w + R1);
  ushort_t* gated   = (ushort_t*)(w + R1);
  float*    core    = (float*)   (w + R2);
  ushort_t* wot     = (ushort_t*)(w + R2);
  float*    ba      = (float*)   (w + R3);
  float2*   egb     = (float2*)  (w + R3 + 1048576);

  cast_x_kernel<<<(MTOT*HID/4 + 255)/256, 256, 0, stream>>>(x, xb, MTOT*HID/4);
  transpose_cast<<<dim3(NQKVZ/64, HID/64), 256, 0, stream>>>(W_qkvz, wqt, HID, NQKVZ);
  gemm_bf16<1><<<dim3(NQKVZ/128, MTOT/128), 256, 0, stream>>>(xb, wqt, (void*)qkvz_bf, MTOT, NQKVZ, HID);
  gemm_ba<<<MTOT/4, 256, 0, stream>>>(x, W_ba, ba);
  gbeta_kernel<<<(MTOT*NV_+255)/256, 256, 0, stream>>>(ba, A_log, dt_bias, egb);
  conv_norm_kernel<<<MTOT*64, 128, 0, stream>>>(qkvz_bf, conv_w, qkv_bf);
  recurrence_v3<<<B_*NV_*8, 512, 0, stream>>>(qkv_bf, egb, core);
  gatenorm_kernel<<<MTOT*NV_, 128, 0, stream>>>(core, qkvz_bf, norm_w, gated);
  transpose_cast<<<dim3(2048/64, 4096/64), 256, 0, stream>>>(W_out, wot, 4096, 2048);
  gemm_bf16<0><<<dim3(2048/128, MTOT/128), 256, 0, stream>>>(gated, wot, (void*)outp, MTOT, 2048, 4096);
}

// Round 13
// 1068.645 us; speedup vs baseline: 1.1521x; 1.1521x over previous
//
#include <hip/hip_runtime.h>
#include <stdint.h>

#define B_    2
#define SEQ   2048
#define HID   2048
#define NK_   16
#define NV_   32
#define DK_   128
#define DV_   128
#define NQKVZ 12288
#define CONVD 8192
#define MTOT  (B_*SEQ)   // 4096
#define CCH   16         // recurrence sub-chunk length

typedef unsigned short ushort_t;
typedef __bf16 bf16x8 __attribute__((ext_vector_type(8)));
typedef float  f32x4  __attribute__((ext_vector_type(4)));
typedef unsigned short us4 __attribute__((ext_vector_type(4)));

__device__ __forceinline__ ushort_t f2bf(float f){
  union { float f; unsigned u; } v; v.f = f;
  unsigned r = v.u + 0x7FFFu + ((v.u >> 16) & 1u);
  return (ushort_t)(r >> 16);
}
__device__ __forceinline__ float bf2f(ushort_t u){
  union { unsigned u; float f; } v; v.u = ((unsigned)u) << 16; return v.f;
}
__device__ __forceinline__ float sigmoidf_(float x){ return 1.f/(1.f+__expf(-x)); }
__device__ __forceinline__ float siluf_(float x){ return x*sigmoidf_(x); }

// ---------------- cast x -> bf16 ----------------
__global__ void cast_x_kernel(const float* __restrict__ x, ushort_t* __restrict__ xb, int n4){
  int i = blockIdx.x*256 + threadIdx.x;
  if (i >= n4) return;
  float4 v = ((const float4*)x)[i];
  us4 o; o[0]=f2bf(v.x); o[1]=f2bf(v.y); o[2]=f2bf(v.z); o[3]=f2bf(v.w);
  ((us4*)xb)[i] = o;
}

// ---------------- transpose + cast W[K][N] -> Wt[N][K] bf16 ----------------
__global__ __launch_bounds__(256) void transpose_cast(const float* __restrict__ W, ushort_t* __restrict__ Wt,
                                                      int K, int N){
  __shared__ float tile[64][65];
  int n0 = blockIdx.x*64, k0 = blockIdx.y*64;
  int tx = threadIdx.x & 63, ty = threadIdx.x >> 6;
  #pragma unroll
  for (int i=0;i<16;i++){
    int kr = ty + i*4;
    tile[kr][tx] = W[(size_t)(k0+kr)*N + n0+tx];
  }
  __syncthreads();
  #pragma unroll
  for (int i=0;i<16;i++){
    int nr = ty + i*4;
    Wt[(size_t)(n0+nr)*K + k0+tx] = f2bf(tile[tx][nr]);
  }
}

// ---------------- bf16 MFMA GEMM (global_load_lds staging + XCD swizzle) ----------------
template<int OUTBF>
__global__ __launch_bounds__(256) void gemm_bf16(const ushort_t* __restrict__ A, const ushort_t* __restrict__ Bt,
                                                 void* __restrict__ Cv, int M, int N, int K){
  __shared__ ushort_t As[128][32];
  __shared__ ushort_t Bs[128][32];
  const int t = threadIdx.x;
  const int lane = t & 63, w = t >> 6;
  const int wm = w >> 1, wn = w & 1;
  // XCD-aware bijective remap of the flat block index (nwg % 8 == 0 at all launches)
  const int gx = gridDim.x;
  const int nwg = gx * gridDim.y;
  const int flat = blockIdx.y*gx + blockIdx.x;
  const int cpx = nwg >> 3;
  const int swz = (flat & 7)*cpx + (flat >> 3);
  const int m0 = (swz / gx) * 128, n0 = (swz % gx) * 128;
  const int srow = lane >> 2;
  const int scol = (lane & 3) * 8;
  const ushort_t* gA0 = &A [(size_t)(m0 +      w*16 + srow)*K + scol];
  const ushort_t* gA1 = &A [(size_t)(m0 + 64 + w*16 + srow)*K + scol];
  const ushort_t* gB0 = &Bt[(size_t)(n0 +      w*16 + srow)*K + scol];
  const ushort_t* gB1 = &Bt[(size_t)(n0 + 64 + w*16 + srow)*K + scol];
  ushort_t* lA0 = &As[     w*16][0];
  ushort_t* lA1 = &As[64 + w*16][0];
  ushort_t* lB0 = &Bs[     w*16][0];
  ushort_t* lB1 = &Bs[64 + w*16][0];
  f32x4 acc[4][4];
  #pragma unroll
  for (int i=0;i<4;i++)
    #pragma unroll
    for (int j=0;j<4;j++) acc[i][j] = (f32x4){0.f,0.f,0.f,0.f};
  const int lr = lane & 15, lk = (lane >> 4) * 8;
  for (int k0 = 0; k0 < K; k0 += 32){
    __builtin_amdgcn_global_load_lds((const __attribute__((address_space(1))) void*)(gA0 + k0),
                                     (__attribute__((address_space(3))) void*)lA0, 16, 0, 0);
    __builtin_amdgcn_global_load_lds((const __attribute__((address_space(1))) void*)(gA1 + k0),
                                     (__attribute__((address_space(3))) void*)lA1, 16, 0, 0);
    __builtin_amdgcn_global_load_lds((const __attribute__((address_space(1))) void*)(gB0 + k0),
                                     (__attribute__((address_space(3))) void*)lB0, 16, 0, 0);
    __builtin_amdgcn_global_load_lds((const __attribute__((address_space(1))) void*)(gB1 + k0),
                                     (__attribute__((address_space(3))) void*)lB1, 16, 0, 0);
    __syncthreads();
    bf16x8 af[4], bfv[4];
    #pragma unroll
    for (int i=0;i<4;i++) af[i]  = *(const bf16x8*)&As[wm*64 + i*16 + lr][lk];
    #pragma unroll
    for (int j=0;j<4;j++) bfv[j] = *(const bf16x8*)&Bs[wn*64 + j*16 + lr][lk];
    #pragma unroll
    for (int i=0;i<4;i++)
      #pragma unroll
      for (int j=0;j<4;j++)
        acc[i][j] = __builtin_amdgcn_mfma_f32_16x16x32_bf16(af[i], bfv[j], acc[i][j], 0, 0, 0);
    __syncthreads();
  }
  const int lg = lane >> 4;
  #pragma unroll
  for (int i=0;i<4;i++)
    #pragma unroll
    for (int j=0;j<4;j++)
      #pragma unroll
      for (int r=0;r<4;r++){
        int m = m0 + wm*64 + i*16 + lg*4 + r;
        int n = n0 + wn*64 + j*16 + lr;
        if (OUTBF) ((ushort_t*)Cv)[(size_t)m*N + n] = f2bf(acc[i][j][r]);
        else       ((float*)Cv)[(size_t)m*N + n]    = acc[i][j][r];
      }
}

// ---------------- ba = x @ W_ba (fp32, N=64) ----------------
__global__ __launch_bounds__(256) void gemm_ba(const float* __restrict__ x, const float* __restrict__ Wba,
                                               float* __restrict__ ba){
  int lane = threadIdx.x & 63;
  int wid  = threadIdx.x >> 6;
  int row  = blockIdx.x*4 + wid;
  const float* xr = x + (size_t)row*HID;
  float acc = 0.f;
  for (int k=0;k<HID;k+=4){
    float4 xv = *(const float4*)&xr[k];
    acc += xv.x * Wba[(size_t)(k+0)*64 + lane];
    acc += xv.y * Wba[(size_t)(k+1)*64 + lane];
    acc += xv.z * Wba[(size_t)(k+2)*64 + lane];
    acc += xv.w * Wba[(size_t)(k+3)*64 + lane];
  }
  ba[(size_t)row*64 + lane] = acc;
}

// ---------------- conv(k=4) + SiLU + q/k RMS-norm (wave-per-head, no LDS/barrier) ----------------
// grid = MTOT*16 blocks of 256; wave wv handles head-group gi = (blk&15)*4 + wv;
// lane e2 covers cols {2*e2, 2*e2+1} -> full 128-col head per wave, shfl-only reduce.
__global__ __launch_bounds__(256) void conv_norm_kernel(const ushort_t* __restrict__ qkvz, const float* __restrict__ conv_w,
                                                        ushort_t* __restrict__ qkv){
  const int blk = blockIdx.x;
  const int bt = blk >> 4;
  const int ts = bt & (SEQ-1);
  const int gi = (blk & 15)*4 + (threadIdx.x >> 6);
  const int e2 = threadIdx.x & 63;
  const int dk = 2*e2;
  int col;
  if (gi < 16)       col = gi*768 + dk;
  else if (gi < 32)  col = (gi-16)*768 + 128 + dk;
  else { int nv = gi-32; col = (nv>>1)*768 + 256 + (nv&1)*128 + dk; }
  const int c = gi*128 + dk;
  const float4 w0 = *(const float4*)&conv_w[(size_t)c*4];
  const float4 w1 = *(const float4*)&conv_w[(size_t)(c+1)*4];
  ushort2 a0 = (ts>=3) ? *(const ushort2*)&qkvz[(size_t)(bt-3)*NQKVZ + col] : make_ushort2(0,0);
  ushort2 a1 = (ts>=2) ? *(const ushort2*)&qkvz[(size_t)(bt-2)*NQKVZ + col] : make_ushort2(0,0);
  ushort2 a2 = (ts>=1) ? *(const ushort2*)&qkvz[(size_t)(bt-1)*NQKVZ + col] : make_ushort2(0,0);
  ushort2 a3 =           *(const ushort2*)&qkvz[(size_t)(bt  )*NQKVZ + col];
  float y0 = siluf_(bf2f(a0.x)*w0.x + bf2f(a1.x)*w0.y + bf2f(a2.x)*w0.z + bf2f(a3.x)*w0.w);
  float y1 = siluf_(bf2f(a0.y)*w1.x + bf2f(a1.y)*w1.y + bf2f(a2.y)*w1.z + bf2f(a3.y)*w1.w);
  float o0 = y0, o1 = y1;
  if (gi < 32){
    float ss = y0*y0 + y1*y1;
    #pragma unroll
    for (int o=1;o<64;o<<=1) ss += __shfl_xor(ss, o);
    float rs = rsqrtf(ss*(1.f/128.f) + 1e-6f);
    float scale = (gi < 16) ? (1.f/128.f) : 0.08838834764831845f; // 1/128 , 1/sqrt(128)
    o0 = y0*rs*scale; o1 = y1*rs*scale;
  }
  ushort2 ov; ov.x = f2bf(o0); ov.y = f2bf(o1);
  *(ushort2*)&qkv[(size_t)bt*CONVD + gi*128 + dk] = ov;
}

// ---------------- {g, beta} as float2 (g in LOG space) ----------------
__global__ void gbeta_kernel(const float* __restrict__ ba, const float* __restrict__ A_log,
                             const float* __restrict__ dt_bias, float2* __restrict__ egb){
  int idx = blockIdx.x*256 + threadIdx.x;
  if (idx >= MTOT*NV_) return;
  int nv = idx & 31;
  int bt = idx >> 5;
  int nk = nv >> 1, r = nv & 1;
  float bg = ba[(size_t)bt*64 + nk*4 + r];
  float ag = ba[(size_t)bt*64 + nk*4 + 2 + r];
  float ad = ag + dt_bias[nv];
  float sp = fmaxf(ad, 0.f) + log1pf(__expf(-fabsf(ad)));
  float g  = -__expf(A_log[nv]) * sp;
  egb[idx] = make_float2(g, sigmoidf_(bg));
}

// ---------------- chunked gated delta-rule on MFMA, software-pipelined (round-8 proven) ----------------
// grid = B*NV*2 = 128 blocks (head x dv-half), 512 threads = 8 waves.
// 3 phases, 3 barriers per chunk; next-chunk K/V/Q/egb prefetched into regs during phase2/3.
__global__ __launch_bounds__(512) void recurrence_chunked(const ushort_t* __restrict__ qkv,
                                                          const float2* __restrict__ egb,
                                                          float* __restrict__ outc){
  const int bi = blockIdx.x;
  const int b    = bi >> 6;
  const int nv   = (bi >> 1) & 31;
  const int half = bi & 1;
  const int nk   = nv >> 1;
  const int t    = threadIdx.x;
  const int lane = t & 63, w = t >> 6;
  const int lr   = lane & 15, hk = lane >> 4;

  __shared__ ushort_t Kl[16*136];
  __shared__ ushort_t S0h[64*136];
  __shared__ ushort_t S0l[64*136];
  __shared__ ushort_t KT[128*40];
  __shared__ ushort_t DT[64*40];
  __shared__ ushort_t Wl[16*40];
  __shared__ float    Al[16*20];        // 16B-aligned rows for float4 reads
  __shared__ float    Ul[16*65];
  __shared__ float    clB[2][16], blB[2][16], eclB[2][16], kslB[2][16], c15B[2];

  // one-time zero init (k-pad regions persist)
  for (int i = t; i < 64*40;  i += 512) DT[i] = 0;
  for (int i = t; i < 128*40; i += 512) KT[i] = 0;
  for (int i = t; i < 16*40;  i += 512) Wl[i] = 0;
  for (int i = t; i < 64*136; i += 512){ S0h[i] = 0; S0l[i] = 0; }

  f32x4 S[4];
  #pragma unroll
  for (int i=0;i<4;i++) S[i] = (f32x4){0.f,0.f,0.f,0.f};
  const int dt  = w >> 1;
  const int dkb = (w & 1) * 4;
  const int ot  = w - 4;                // output dv-tile for w>=4
  const int st  = t >> 5, sdk = (t & 31) * 4;
  const size_t bt0 = (size_t)b*SEQ;
  const int mytile = (w < 4) ? w : (w - 4);

  // -------- prologue: load chunk 0 into regs, stage, prefix --------
  uint2 kreg = *(const uint2*)(qkv + (bt0+st)*CONVD + 2048 + nk*128 + sdk);
  bf16x8 qf[4];
  if (w >= 4){
    const ushort_t* qrow = qkv + (bt0+lr)*CONVD + nk*128 + hk*8;
    #pragma unroll
    for (int ks=0;ks<4;ks++) qf[ks] = *(const bf16x8*)(qrow + ks*32);
  }
  ushort_t vreg[4];
  if (w < 4){
    #pragma unroll
    for (int r=0;r<4;r++)
      vreg[r] = qkv[(bt0+hk*4+r)*CONVD + 4096 + nv*128 + half*64 + w*16 + lr];
  }
  {
    float2 gb = make_float2(0.f,0.f);
    if (w==1 && lane<16) gb = egb[(bt0+lane)*NV_ + nv];
    *(uint2*)&Kl[st*136 + sdk] = kreg;
    if (w==1 && lane<16){
      float c = gb.x;
      #pragma unroll
      for (int o=1;o<16;o<<=1){ float tv = __shfl_up(c, o, 16); if (lane >= o) c += tv; }
      clB[0][lane] = c; blB[0][lane] = gb.y; eclB[0][lane] = __expf(c);
      float c15 = __shfl(c, 15, 16);
      kslB[0][lane] = __expf(c15 - c);
      if (lane==0) c15B[0] = c15;
    }
  }
  __syncthreads();

  int pb = 0;
  for (int base = 0; base < SEQ; base += CCH){
    const int nbase = (base + CCH < SEQ) ? base + CCH : base;

    // ================= phase 1: products + A/W/u/KT builds =================
    bf16x8 kf[4];
    if (w <= 4){
      #pragma unroll
      for (int ks=0;ks<4;ks++) kf[ks] = *(const bf16x8*)&Kl[lr*136 + hk*8 + ks*32];
    }
    f32x4 ph = (f32x4){0.f,0.f,0.f,0.f}, pl = ph;
    #pragma unroll
    for (int ks=0;ks<4;ks++){
      bf16x8 xf = (w < 4) ? kf[ks] : qf[ks];
      bf16x8 yh = *(const bf16x8*)&S0h[(mytile*16+lr)*136 + hk*8 + ks*32];
      bf16x8 yl = *(const bf16x8*)&S0l[(mytile*16+lr)*136 + hk*8 + ks*32];
      ph = __builtin_amdgcn_mfma_f32_16x16x32_bf16(xf, yh, ph, 0,0,0);
      pl = __builtin_amdgcn_mfma_f32_16x16x32_bf16(xf, yl, pl, 0,0,0);
    }
    if (w == 1){ // A build
      f32x4 a = (f32x4){0.f,0.f,0.f,0.f};
      #pragma unroll
      for (int ks=0;ks<4;ks++) a = __builtin_amdgcn_mfma_f32_16x16x32_bf16(kf[ks], kf[ks], a, 0,0,0);
      #pragma unroll
      for (int r=0;r<4;r++){
        int i = hk*4 + r, j = lr;
        Al[i*20 + j] = (j < i) ? blB[pb][i]*__expf(clB[pb][i]-clB[pb][j])*a[r] : 0.f;
      }
    }
    if (w == 4){ // W build
      f32x4 a = (f32x4){0.f,0.f,0.f,0.f};
      #pragma unroll
      for (int ks=0;ks<4;ks++) a = __builtin_amdgcn_mfma_f32_16x16x32_bf16(qf[ks], kf[ks], a, 0,0,0);
      #pragma unroll
      for (int r=0;r<4;r++){
        int i = hk*4 + r, j = lr;
        float val = (j <= i) ? __expf(clB[pb][i]-clB[pb][j])*a[r] : 0.f;
        Wl[i*40 + j] = f2bf(val);
      }
    }
    if (w < 4){ // u build (v from prefetched regs)
      #pragma unroll
      for (int r=0;r<4;r++){
        int i = hk*4 + r;
        Ul[i*65 + w*16 + lr] = blB[pb][i]*(bf2f(vreg[r]) - eclB[pb][i]*(ph[r] + pl[r]));
      }
    }
    if (w == 2 || w == 3){ // K'^T build
      int dk = t & 127;
      #pragma unroll
      for (int j=0;j<16;j+=2){
        unsigned p0 = f2bf(kslB[pb][j]  * bf2f(Kl[j*136     + dk]));
        unsigned p1 = f2bf(kslB[pb][j+1]* bf2f(Kl[(j+1)*136 + dk]));
        *(unsigned*)&KT[dk*40 + j] = p0 | (p1 << 16);
      }
    }
    __syncthreads();   // B3: A,W,u,KT ready

    // ================= phase 2: substitution (w0) || prefetch next (others) =================
    kreg = *(const uint2*)(qkv + (bt0+nbase+st)*CONVD + 2048 + nk*128 + sdk);
    if (w >= 4){
      const ushort_t* qrow = qkv + (bt0 + nbase + lr)*CONVD + nk*128 + hk*8;
      #pragma unroll
      for (int ks=0;ks<4;ks++) qf[ks] = *(const bf16x8*)(qrow + ks*32);
    }
    if (w < 4){
      #pragma unroll
      for (int r=0;r<4;r++)
        vreg[r] = qkv[(bt0+nbase+hk*4+r)*CONVD + 4096 + nv*128 + half*64 + w*16 + lr];
    }
    float2 ebn = make_float2(0.f,0.f);
    if (w==1 && lane<16) ebn = egb[(bt0+nbase+lane)*NV_ + nv];
    // pre-read fragments consumed in phase 3
    bf16x8 yf[4];
    #pragma unroll
    for (int tt=0;tt<4;tt++) yf[tt] = *(const bf16x8*)&KT[((dkb+tt)*16+lr)*40 + hk*8];
    bf16x8 wfr;
    if (w >= 4) wfr = *(const bf16x8*)&Wl[lr*40 + hk*8];

    if (w == 0){ // blocked forward substitution, column = lane
      float d[16];
      #pragma unroll
      for (int r=0;r<16;r++) d[r] = Ul[r*65 + lane];
      #pragma unroll
      for (int rb=0;rb<4;rb++){
        float p0=0.f,p1=0.f,p2=0.f,p3=0.f;
        #pragma unroll
        for (int jb=0;jb<rb;jb++){
          float4 A0 = *(const float4*)&Al[(rb*4+0)*20 + jb*4];
          float4 A1 = *(const float4*)&Al[(rb*4+1)*20 + jb*4];
          float4 A2 = *(const float4*)&Al[(rb*4+2)*20 + jb*4];
          float4 A3 = *(const float4*)&Al[(rb*4+3)*20 + jb*4];
          p0 += A0.x*d[jb*4]+A0.y*d[jb*4+1]+A0.z*d[jb*4+2]+A0.w*d[jb*4+3];
          p1 += A1.x*d[jb*4]+A1.y*d[jb*4+1]+A1.z*d[jb*4+2]+A1.w*d[jb*4+3];
          p2 += A2.x*d[jb*4]+A2.y*d[jb*4+1]+A2.z*d[jb*4+2]+A2.w*d[jb*4+3];
          p3 += A3.x*d[jb*4]+A3.y*d[jb*4+1]+A3.z*d[jb*4+2]+A3.w*d[jb*4+3];
        }
        const int r0 = rb*4;
        d[r0+0] -= p0;
        d[r0+1] -= p1 + Al[(r0+1)*20+r0]*d[r0];
        d[r0+2] -= p2 + Al[(r0+2)*20+r0]*d[r0] + Al[(r0+2)*20+r0+1]*d[r0+1];
        d[r0+3] -= p3 + Al[(r0+3)*20+r0]*d[r0] + Al[(r0+3)*20+r0+1]*d[r0+1] + Al[(r0+3)*20+r0+2]*d[r0+2];
      }
      unsigned dd[8];
      #pragma unroll
      for (int p=0;p<8;p++) dd[p] = (unsigned)f2bf(d[2*p]) | ((unsigned)f2bf(d[2*p+1]) << 16);
      *(uint4*)&DT[lane*40 + 0] = make_uint4(dd[0],dd[1],dd[2],dd[3]);
      *(uint4*)&DT[lane*40 + 8] = make_uint4(dd[4],dd[5],dd[6],dd[7]);
    }
    __syncthreads();   // B4: Delta ready

    // ================= phase 3: O + state update + writebacks + next staging =================
    if (w >= 4){
      bf16x8 dfr = *(const bf16x8*)&DT[(ot*16+lr)*40 + hk*8];
      f32x4 oo = __builtin_amdgcn_mfma_f32_16x16x32_bf16(wfr, dfr, (f32x4){0.f,0.f,0.f,0.f}, 0,0,0);
      #pragma unroll
      for (int r=0;r<4;r++){
        int i = hk*4 + r;
        outc[((bt0+base+i)*NV_ + nv)*(size_t)DV_ + half*64 + ot*16 + lr] = oo[r] + eclB[pb][i]*(ph[r] + pl[r]);
      }
    }
    {
      float g15 = __expf(c15B[pb]);
      bf16x8 xf2 = *(const bf16x8*)&DT[(dt*16+lr)*40 + hk*8];
      #pragma unroll
      for (int tt=0;tt<4;tt++){
        f32x4 s = S[tt];
        s[0]*=g15; s[1]*=g15; s[2]*=g15; s[3]*=g15;
        S[tt] = __builtin_amdgcn_mfma_f32_16x16x32_bf16(xf2, yf[tt], s, 0,0,0);
      }
    }
    #pragma unroll
    for (int tt=0;tt<4;tt++){
      #pragma unroll
      for (int r=0;r<4;r++){
        int dvrow = dt*16 + hk*4 + r;
        int dkcol = (dkb+tt)*16 + lr;
        float sv = S[tt][r];
        ushort_t h = f2bf(sv);
        S0h[dvrow*136 + dkcol] = h;
        S0l[dvrow*136 + dkcol] = f2bf(sv - bf2f(h));
      }
    }
    *(uint2*)&Kl[st*136 + sdk] = kreg;   // stage next chunk's K
    if (w==1 && lane<16){                 // next chunk's prefix
      float c = ebn.x;
      #pragma unroll
      for (int o=1;o<16;o<<=1){ float tv = __shfl_up(c, o, 16); if (lane >= o) c += tv; }
      clB[pb^1][lane] = c; blB[pb^1][lane] = ebn.y; eclB[pb^1][lane] = __expf(c);
      float c15 = __shfl(c, 15, 16);
      kslB[pb^1][lane] = __expf(c15 - c);
      if (lane==0) c15B[pb^1] = c15;
    }
    __syncthreads();   // B5: S0/Kl/prefix ready for next chunk
    pb ^= 1;
  }
}

// ---------------- gated RMSNorm -> bf16 ----------------
__global__ __launch_bounds__(128) void gatenorm_kernel(const float* __restrict__ outc, const ushort_t* __restrict__ qkvz,
                                                       const float* __restrict__ norm_w, ushort_t* __restrict__ gated){
  __shared__ float red[2];
  const int blk = blockIdx.x;
  const int nv = blk & 31;
  const size_t bt = (size_t)(blk >> 5);
  const int dv = threadIdx.x;
  float xv = outc[(bt*NV_ + nv)*(size_t)DV_ + dv];
  float ss = xv*xv;
  #pragma unroll
  for (int o=1;o<64;o<<=1) ss += __shfl_xor(ss, o);
  if ((threadIdx.x & 63)==0) red[threadIdx.x>>6] = ss;
  __syncthreads();
  float tot = red[0]+red[1];
  float xn = xv * rsqrtf(tot*(1.f/128.f) + 1e-6f) * norm_w[dv];
  int nk = nv>>1, r = nv&1;
  float z = bf2f(qkvz[bt*NQKVZ + nk*768 + 512 + r*128 + dv]);
  gated[bt*(size_t)4096 + nv*128 + dv] = f2bf(siluf_(z)*xn);
}

extern "C" void kernel_launch(void* const* d_in, const int* in_sizes, int n_in,
                              void* d_out, int out_size, void* d_ws, size_t ws_size,
                              hipStream_t stream){
  (void)in_sizes; (void)n_in; (void)out_size; (void)ws_size;
  const float* x      = (const float*)d_in[0];
  const float* W_qkvz = (const float*)d_in[1];
  const float* W_ba   = (const float*)d_in[2];
  const float* conv_w = (const float*)d_in[3];
  const float* dt_bias= (const float*)d_in[4];
  const float* A_log  = (const float*)d_in[5];
  const float* norm_w = (const float*)d_in[6];
  const float* W_out  = (const float*)d_in[7];
  float* outp = (float*)d_out;

  char* w = (char*)d_ws;
  const size_t R0 = 0;
  const size_t R1 = 100663296;
  const size_t R2 = R1 + 67108864;
  const size_t R3 = R2 + 67108864;
  ushort_t* qkvz_bf = (ushort_t*)(w + R0);
  ushort_t* xb      = (ushort_t*)(w + R1);
  ushort_t* wqt     = (ushort_t*)(w + R1 + 16777216);
  ushort_t* qkv_bf  = (ushort_t*)(w + R1);
  ushort_t* gated   = (ushort_t*)(w + R1);
  float*    core    = (float*)   (w + R2);
  ushort_t* wot     = (ushort_t*)(w + R2);
  float*    ba      = (float*)   (w + R3);
  float2*   egb     = (float2*)  (w + R3 + 1048576);

  cast_x_kernel<<<(MTOT*HID/4 + 255)/256, 256, 0, stream>>>(x, xb, MTOT*HID/4);
  transpose_cast<<<dim3(NQKVZ/64, HID/64), 256, 0, stream>>>(W_qkvz, wqt, HID, NQKVZ);
  gemm_bf16<1><<<dim3(NQKVZ/128, MTOT/128), 256, 0, stream>>>(xb, wqt, (void*)qkvz_bf, MTOT, NQKVZ, HID);
  gemm_ba<<<MTOT/4, 256, 0, stream>>>(x, W_ba, ba);
  gbeta_kernel<<<(MTOT*NV_+255)/256, 256, 0, stream>>>(ba, A_log, dt_bias, egb);
  conv_norm_kernel<<<MTOT*16, 256, 0, stream>>>(qkvz_bf, conv_w, qkv_bf);
  recurrence_chunked<<<B_*NV_*2, 512, 0, stream>>>(qkv_bf, egb, core);
  gatenorm_kernel<<<MTOT*NV_, 128, 0, stream>>>(core, qkvz_bf, norm_w, gated);
  transpose_cast<<<dim3(2048/64, 4096/64), 256, 0, stream>>>(W_out, wot, 4096, 2048);
  gemm_bf16<0><<<dim3(2048/128, MTOT/128), 256, 0, stream>>>(gated, wot, (void*)outp, MTOT, 2048, 4096);
}